// Round 1
// baseline (70.834 us; speedup 1.0000x reference)
//
#include <hip/hip_runtime.h>

// TT-core contraction: C[a,c,i,k,b,d] = sum_j A[a,i,j,b] * B[c,j,k,d]
// A: [RA0, M, N, RA1], B: [RB0, N, P, RB1], C flat: [RA0*RB0, M, P, RA1*RB1]
// Flat C index: ((((a*RB0 + c)*M + i)*P + k)*RA1 + b)*RB1 + d
//
// Vectorized 4-wide along d (requires RB1 % 4 == 0). Each thread computes one
// float4 of output -> 16B/lane coalesced stores; inputs are tiny (~1.8MB
// total) and served from L1/L2 after first touch. Write-BW-bound kernel.

template<int RA0, int M, int N, int RA1, int RB0, int P, int RB1>
__device__ __forceinline__ void tt_core_v4(
    const float* __restrict__ A, const float* __restrict__ B,
    float* __restrict__ C, int v, int total_vec)
{
    if (v >= total_vec) return;
    constexpr int RB1V   = RB1 / 4;        // float4 groups along d
    constexpr int INNER_V = RA1 * RB1V;    // vec elements per (a,c,i,k) slab

    const int iv    = v % INNER_V;
    const int outer = v / INNER_V;
    const int d4 = iv % RB1V;
    const int b  = iv / RB1V;
    const int k  = outer % P;
    const int t  = outer / P;
    const int i  = t % M;
    const int t2 = t / M;
    const int c  = t2 % RB0;
    const int a  = t2 / RB0;

    const float* Ap = A + ((a * M + i) * N) * RA1 + b;          // + j*RA1
    const float* Bp = B + ((c * N) * P + k) * RB1 + d4 * 4;     // + j*P*RB1

    float4 acc = make_float4(0.f, 0.f, 0.f, 0.f);
#pragma unroll
    for (int j = 0; j < N; ++j) {
        const float  aj = Ap[j * RA1];
        const float4 bv = *reinterpret_cast<const float4*>(Bp + j * P * RB1);
        acc.x = fmaf(aj, bv.x, acc.x);
        acc.y = fmaf(aj, bv.y, acc.y);
        acc.z = fmaf(aj, bv.z, acc.z);
        acc.w = fmaf(aj, bv.w, acc.w);
    }
    reinterpret_cast<float4*>(C)[v] = acc;
}

// Output sizes (f32 elements) and flat offsets in d_out:
//  core0: [1,   8, 1, 1024] =     8192   @ 0
//  core1: [1024,8, 2, 1024] = 16777216   @ 8192
//  core2: [1024,8, 5, 1024] = 41943040   @ 16785408
//  core3: [1024,4, 1, 1024] =  4194304   @ 58728448
//  core4: [1024,2, 1,    1] =     2048   @ 62922752
// Block budget (256 thr, 4 outs/thr for cores 0-3, 1 out/thr for core 4):
//  core2: 40960, core1: 16384, core3: 4096, core0: 8, core4: 8 -> 61456 blocks

#define NBLK2 40960
#define NBLK1 16384
#define NBLK3 4096
#define NBLK0 8
#define NBLK4 8
#define NBLK_TOTAL (NBLK2 + NBLK1 + NBLK3 + NBLK0 + NBLK4)

__global__ __launch_bounds__(256) void fused_tt_kernel(
    const float* __restrict__ x0, const float* __restrict__ x1,
    const float* __restrict__ x2, const float* __restrict__ x3,
    const float* __restrict__ x4,
    const float* __restrict__ w0, const float* __restrict__ w1,
    const float* __restrict__ w2, const float* __restrict__ w3,
    const float* __restrict__ w4,
    float* __restrict__ out)
{
    const int blk = blockIdx.x;
    const int tid = threadIdx.x;

    if (blk < NBLK2) {
        // core2: x2 [64,8,8,64] * w2 [16,8,5,16]
        tt_core_v4<64, 8, 8, 64, 16, 5, 16>(
            x2, w2, out + 16785408, blk * 256 + tid, 10485760);
    } else if (blk < NBLK2 + NBLK1) {
        // core1: x1 [64,8,4,64] * w1 [16,4,2,16]
        tt_core_v4<64, 8, 4, 64, 16, 2, 16>(
            x1, w1, out + 8192, (blk - NBLK2) * 256 + tid, 4194304);
    } else if (blk < NBLK2 + NBLK1 + NBLK3) {
        // core3: x3 [64,4,4,64] * w3 [16,4,1,16]
        tt_core_v4<64, 4, 4, 64, 16, 1, 16>(
            x3, w3, out + 58728448, (blk - NBLK2 - NBLK1) * 256 + tid, 1048576);
    } else if (blk < NBLK2 + NBLK1 + NBLK3 + NBLK0) {
        // core0: x0 [1,8,3,64] * w0 [1,3,1,16]
        tt_core_v4<1, 8, 3, 64, 1, 1, 16>(
            x0, w0, out, (blk - NBLK2 - NBLK1 - NBLK3) * 256 + tid, 2048);
    } else {
        // core4 (scalar, rb1=1): x4 [64,2,8,1] * w4 [16,8,1,1]
        // out4[o], o = (a*16 + c)*2 + i ; val = sum_j x4[(a*2+i)*8+j] * w4[c*8+j]
        const int o = (blk - NBLK2 - NBLK1 - NBLK3 - NBLK0) * 256 + tid;
        if (o < 2048) {
            const int i = o % 2;
            const int t = o / 2;
            const int c = t % 16;
            const int a = t / 16;
            float acc = 0.f;
#pragma unroll
            for (int j = 0; j < 8; ++j)
                acc = fmaf(x4[(a * 2 + i) * 8 + j], w4[c * 8 + j], acc);
            out[62922752 + o] = acc;
        }
    }
}

extern "C" void kernel_launch(void* const* d_in, const int* in_sizes, int n_in,
                              void* d_out, int out_size, void* d_ws, size_t ws_size,
                              hipStream_t stream) {
    const float* x0 = (const float*)d_in[0];
    const float* x1 = (const float*)d_in[1];
    const float* x2 = (const float*)d_in[2];
    const float* x3 = (const float*)d_in[3];
    const float* x4 = (const float*)d_in[4];
    const float* w0 = (const float*)d_in[5];
    const float* w1 = (const float*)d_in[6];
    const float* w2 = (const float*)d_in[7];
    const float* w3 = (const float*)d_in[8];
    const float* w4 = (const float*)d_in[9];
    float* out = (float*)d_out;

    fused_tt_kernel<<<NBLK_TOTAL, 256, 0, stream>>>(
        x0, x1, x2, x3, x4, w0, w1, w2, w3, w4, out);
}